// Round 7
// baseline (386.433 us; speedup 1.0000x reference)
//
#include <hip/hip_runtime.h>
#include <hip/hip_bf16.h>

#define NNODES 50000
#define NEDGES 500000
#define INCH 128
#define HID 64
#define HEADS 4
#define FDIM 256
#define NGRAPHS 64
#define OUTCH 16
#define NEG_SLOPE 0.2f

#define BM 128
#define BN 256
#define BK 32

typedef float f32x4 __attribute__((ext_vector_type(4)));
typedef _Float16 f16x8 __attribute__((ext_vector_type(8)));
typedef _Float16 f16x4 __attribute__((ext_vector_type(4)));

__device__ inline void gld_lds16(const void* g, void* l) {
    __builtin_amdgcn_global_load_lds((__attribute__((address_space(1))) void*)g,
                                     (__attribute__((address_space(3))) void*)l, 16, 0, 0);
}

// ---------------- CSR build ----------------

__global__ void k_hist(const int* __restrict__ dst, int E, int* __restrict__ counts) {
    int i = blockIdx.x * blockDim.x + threadIdx.x;
    if (i < E) atomicAdd(&counts[dst[i]], 1);
}

__global__ __launch_bounds__(256) void k_blocksum(const int* __restrict__ counts, int N,
                                                  int* __restrict__ bsum) {
    int idx = blockIdx.x * 256 + threadIdx.x;
    int v = (idx < N) ? counts[idx] : 0;
#pragma unroll
    for (int off = 32; off; off >>= 1) v += __shfl_xor(v, off);
    __shared__ int wsum[4];
    if ((threadIdx.x & 63) == 0) wsum[threadIdx.x >> 6] = v;
    __syncthreads();
    if (threadIdx.x == 0) bsum[blockIdx.x] = wsum[0] + wsum[1] + wsum[2] + wsum[3];
}

__global__ __launch_bounds__(256) void k_scanfinal(const int* __restrict__ counts,
                                                   const int* __restrict__ bsum, int N,
                                                   int* __restrict__ rowstart,
                                                   int* __restrict__ cursor) {
    __shared__ int tmp[256];
    __shared__ int wsum[4];
    int t = threadIdx.x, b = blockIdx.x;
    int p = 0;
    for (int i = t; i < b; i += 256) p += bsum[i];
#pragma unroll
    for (int off = 32; off; off >>= 1) p += __shfl_xor(p, off);
    int idx = b * 256 + t;
    int v = (idx < N) ? counts[idx] : 0;
    tmp[t] = v;
    if ((t & 63) == 0) wsum[t >> 6] = p;
    __syncthreads();
    int bp = wsum[0] + wsum[1] + wsum[2] + wsum[3];
    for (int off = 1; off < 256; off <<= 1) {
        int u = (t >= off) ? tmp[t - off] : 0;
        __syncthreads();
        tmp[t] += u;
        __syncthreads();
    }
    if (idx < N) {
        int incl = bp + tmp[t];
        rowstart[idx + 1] = incl;
        cursor[idx] = incl - v;
    }
    if (idx == 0) rowstart[0] = 0;
}

__global__ void k_scatter(const int* __restrict__ src, const int* __restrict__ dst, int E,
                          int* __restrict__ cursor, int* __restrict__ csr_src) {
    int i = blockIdx.x * blockDim.x + threadIdx.x;
    if (i < E) {
        int p = atomicAdd(&cursor[dst[i]], 1);
        csr_src[p] = src[i];
    }
}

// ---------------- weight transpose to f16: W[K][256] -> Wt[256][K] ----------------

__global__ void k_wdecomp(const float* __restrict__ W, _Float16* __restrict__ Wt, int K) {
    int i = blockIdx.x * 256 + threadIdx.x;
    if (i >= K * 256) return;
    int k = i >> 8, n = i & 255;
    Wt[n * K + k] = (_Float16)W[i];
}

// ---------------- x -> f16 plane ----------------

__global__ void k_adecomp(const float* __restrict__ X, _Float16* __restrict__ Xf, int total4) {
    int i = blockIdx.x * 256 + threadIdx.x;
    if (i >= total4) return;
    float4 v = ((const float4*)X)[i];
    f16x4 o = {(_Float16)v.x, (_Float16)v.y, (_Float16)v.z, (_Float16)v.w};
    ((f16x4*)Xf)[i] = o;
}

// ---------------- f16 MFMA GEMM, BM=128, double-buffered gld_lds, fused scores ----------------
// LDS linear [rows][BK], 16B-chunk swizzle sc = lc ^ ((row>>1)&3) applied on the global
// source address (gld_lds writes linearly) and on the ds_read chunk index.
// Note ((row+64k)>>1)&3 == ((row)>>1)&3 for the rows a given lane stages, so one 'alc'
// serves all staging rounds.

__global__ __launch_bounds__(256, 2) void k_gemm_mfma(
    const _Float16* __restrict__ A, const _Float16* __restrict__ B,
    const float* __restrict__ av, const float* __restrict__ dv,
    _Float16* __restrict__ Hf,
    float* __restrict__ ssrcO, float* __restrict__ sdstO, int M, int K) {
    __shared__ _Float16 sA[2][BM * BK];   // 8 KB each
    __shared__ _Float16 sB[2][BN * BK];   // 16 KB each

    const int t = threadIdx.x;
    const int row0 = blockIdx.x * BM;
    const int wv = t >> 6, ln = t & 63, lr = ln & 15, lk = ln >> 4;

    const int ar = wv * 16 + (ln >> 2);              // staged row (mod 64)
    const int alc = (ln & 3) ^ ((ar >> 1) & 3);      // logical 16B chunk to fetch
    const size_t agoff0 = (size_t)min(row0 + ar, M - 1) * K + alc * 8;
    const size_t agoff1 = (size_t)min(row0 + ar + 64, M - 1) * K + alc * 8;
    const int fsc = lk ^ ((lr >> 1) & 3);            // fragment-read stored chunk

    f32x4 acc[8][4] = {};
    const int nt = K / BK;

#define STAGE(tt, p)                                                        \
    do {                                                                    \
        int _k0 = (tt)*BK;                                                  \
        gld_lds16(A + agoff0 + _k0, &sA[p][wv * 512]);                      \
        gld_lds16(A + agoff1 + _k0, &sA[p][2048 + wv * 512]);               \
        _Pragma("unroll") for (int _j = 0; _j < 4; ++_j) {                  \
            int _br = _j * 64 + ar;                                         \
            gld_lds16(B + (size_t)_br * K + _k0 + alc * 8,                  \
                      &sB[p][_j * 2048 + wv * 512]);                        \
        }                                                                   \
    } while (0)

    STAGE(0, 0);
    __syncthreads();
    for (int tt = 0; tt < nt; ++tt) {
        int cur = tt & 1;
        if (tt + 1 < nt) STAGE(tt + 1, cur ^ 1);  // in flight during compute

        f16x8 af[8];
#pragma unroll
        for (int mi = 0; mi < 8; ++mi)
            af[mi] = *(const f16x8*)&sA[cur][(mi * 16 + lr) * BK + fsc * 8];
#pragma unroll
        for (int ni = 0; ni < 4; ++ni) {
            f16x8 bf = *(const f16x8*)&sB[cur][(wv * 64 + ni * 16 + lr) * BK + fsc * 8];
#pragma unroll
            for (int mi = 0; mi < 8; ++mi)
                acc[mi][ni] = __builtin_amdgcn_mfma_f32_16x16x32_f16(af[mi], bf, acc[mi][ni], 0, 0, 0);
        }
        __syncthreads();
    }
#undef STAGE

    // ---- epilogue: f16 H store + fused score partials (per-mi to limit registers) ----
    float avr[4], dvr[4];
#pragma unroll
    for (int ni = 0; ni < 4; ++ni) {
        int col = wv * 64 + ni * 16 + lr;
        avr[ni] = av[col];
        dvr[ni] = dv[col];
    }
#pragma unroll
    for (int mi = 0; mi < 8; ++mi) {
        float ps[4] = {}, pd[4] = {};
        int rbase = row0 + mi * 16 + lk * 4;
#pragma unroll
        for (int ni = 0; ni < 4; ++ni) {
            int col = wv * 64 + ni * 16 + lr;
            f32x4 v = acc[mi][ni];
#pragma unroll
            for (int j = 0; j < 4; ++j) {
                if (rbase + j < M) Hf[(size_t)(rbase + j) * FDIM + col] = (_Float16)v[j];
                ps[j] += v[j] * avr[ni];
                pd[j] += v[j] * dvr[ni];
            }
        }
#pragma unroll
        for (int j = 0; j < 4; ++j) {
            float s = ps[j], q = pd[j];
            s += __shfl_xor(s, 1); s += __shfl_xor(s, 2);
            s += __shfl_xor(s, 4); s += __shfl_xor(s, 8);
            q += __shfl_xor(q, 1); q += __shfl_xor(q, 2);
            q += __shfl_xor(q, 4); q += __shfl_xor(q, 8);
            if (lr == 0 && rbase + j < M) {
                ssrcO[(rbase + j) * HEADS + wv] = s;
                sdstO[(rbase + j) * HEADS + wv] = q;
            }
        }
    }
}

// ---------------- softmax prep: one thread per (node, head); scores are L2-resident ----------------
// Writes pre-normalized alpha into CSR order (wcsr[r][h]) and self-loop alpha.

__global__ __launch_bounds__(256) void k_edgew(
    const float* __restrict__ ssrc, const float* __restrict__ sdst,
    const int* __restrict__ rowstart, const int* __restrict__ csr_src,
    float* __restrict__ wcsr, float* __restrict__ aself, int N) {
    int tid = blockIdx.x * 256 + threadIdx.x;
    int n = tid >> 2, h = tid & 3;
    if (n >= N) return;
    int r0 = rowstart[n], r1 = rowstart[n + 1];
    float sd = sdst[n * HEADS + h];
    float es = ssrc[n * HEADS + h] + sd;
    es = (es > 0.f) ? es : NEG_SLOPE * es;
    float m = es;
    for (int r = r0; r < r1; ++r) {
        int s = csr_src[r];
        float sc = ssrc[s * HEADS + h] + sd;
        sc = (sc > 0.f) ? sc : NEG_SLOPE * sc;
        m = fmaxf(m, sc);
    }
    float denom = __expf(es - m);
    for (int r = r0; r < r1; ++r) {
        int s = csr_src[r];
        float sc = ssrc[s * HEADS + h] + sd;
        sc = (sc > 0.f) ? sc : NEG_SLOPE * sc;
        float w = __expf(sc - m);
        wcsr[r * HEADS + h] = w;
        denom += w;
    }
    float inv = 1.0f / denom;
    aself[n * HEADS + h] = __expf(es - m) * inv;
    for (int r = r0; r < r1; ++r) wcsr[r * HEADS + h] *= inv;
}

// ---------------- aggregation: pure weighted gather-sum (alphas precomputed) ----------------

__global__ __launch_bounds__(256) void k_aggregate(
    const _Float16* __restrict__ hf,
    const float* __restrict__ wcsr, const float* __restrict__ aself,
    const int* __restrict__ rowstart, const int* __restrict__ csr_src,
    const float* __restrict__ bias,
    _Float16* __restrict__ outf, int N) {
    int wv = threadIdx.x >> 6, ln = threadIdx.x & 63;
    int n = blockIdx.x * 4 + wv;
    if (n >= N) return;
    int head = ln >> 4;
    int fo = head * 64 + (ln & 15) * 4;
    float a0 = aself[n * HEADS + head];
    f16x4 sv = *(const f16x4*)&hf[(size_t)n * FDIM + fo];
    float4 acc = make_float4(a0 * (float)sv[0], a0 * (float)sv[1],
                             a0 * (float)sv[2], a0 * (float)sv[3]);
    int r0 = rowstart[n], r1 = rowstart[n + 1];
    int cnt = r1 - r0;
    for (int base = 0; base < cnt; base += 8) {
        int s[8];
        float w[8];
        f16x4 u[8];
#pragma unroll
        for (int i = 0; i < 8; ++i) {
            int rr = min(r0 + base + i, r1 - 1);
            s[i] = csr_src[rr];
            w[i] = wcsr[rr * HEADS + head];
        }
#pragma unroll
        for (int i = 0; i < 8; ++i) u[i] = *(const f16x4*)&hf[(size_t)s[i] * FDIM + fo];
#pragma unroll
        for (int i = 0; i < 8; ++i) w[i] = (base + i < cnt) ? w[i] : 0.f;
#pragma unroll
        for (int i = 0; i < 8; ++i) {
            acc.x += w[i] * (float)u[i][0];
            acc.y += w[i] * (float)u[i][1];
            acc.z += w[i] * (float)u[i][2];
            acc.w += w[i] * (float)u[i][3];
        }
    }
    float4 bv = *(const float4*)&bias[fo];
    f16x4 o;
    o[0] = (_Float16)fmaxf(acc.x + bv.x, 0.f);
    o[1] = (_Float16)fmaxf(acc.y + bv.y, 0.f);
    o[2] = (_Float16)fmaxf(acc.z + bv.z, 0.f);
    o[3] = (_Float16)fmaxf(acc.w + bv.w, 0.f);
    *(f16x4*)&outf[(size_t)n * FDIM + fo] = o;
}

// ---------------- pooling (batch sorted, f16 plane) ----------------

__global__ __launch_bounds__(256) void k_pool(const _Float16* __restrict__ hf,
                                              const int* __restrict__ batch,
                                              float* __restrict__ pooled, int N) {
    int f = threadIdx.x;
    int n0 = blockIdx.x * 128;
    if (n0 >= N) return;
    int n1 = min(n0 + 128, N);
    int g = batch[n0];
    float run = 0.f;
    for (int n = n0; n < n1; ++n) {
        int gn = batch[n];
        if (gn != g) {
            atomicAdd(&pooled[g * FDIM + f], run);
            run = 0.f;
            g = gn;
        }
        run += (float)hf[(size_t)n * FDIM + f];
    }
    atomicAdd(&pooled[g * FDIM + f], run);
}

// ---------------- final classifier ----------------

__global__ __launch_bounds__(256) void k_final(const float* __restrict__ pooled,
                                               const float* __restrict__ Wc,
                                               const float* __restrict__ bc,
                                               float* __restrict__ out) {
    int tid = blockIdx.x * 256 + threadIdx.x;
    int g = tid >> 4, o = tid & 15;
    float s = bc[o];
    for (int k = 0; k < FDIM; ++k) s += pooled[g * FDIM + k] * Wc[k * OUTCH + o];
    out[g * OUTCH + o] = s;
}

// ---------------- launch ----------------

extern "C" void kernel_launch(void* const* d_in, const int* in_sizes, int n_in,
                              void* d_out, int out_size, void* d_ws, size_t ws_size,
                              hipStream_t stream) {
    const float* x = (const float*)d_in[0];
    const int* edge_index = (const int*)d_in[2];
    const int* batch = (const int*)d_in[3];
    const float* W[3]    = {(const float*)d_in[4], (const float*)d_in[8],  (const float*)d_in[12]};
    const float* asrc[3] = {(const float*)d_in[5], (const float*)d_in[9],  (const float*)d_in[13]};
    const float* adst[3] = {(const float*)d_in[6], (const float*)d_in[10], (const float*)d_in[14]};
    const float* bias[3] = {(const float*)d_in[7], (const float*)d_in[11], (const float*)d_in[15]};
    const float* Wc = (const float*)d_in[16];
    const float* bc = (const float*)d_in[17];

    const int N = in_sizes[3];
    const int E = in_sizes[2] / 2;
    const int* e_src = edge_index;
    const int* e_dst = edge_index + E;

    char* ws = (char*)d_ws;
    size_t off = 0;
    _Float16* hb = (_Float16*)(ws + off); off += (size_t)N * FDIM * 2;   // 25.6 MB
    _Float16* xf = (_Float16*)(ws + off); off += (size_t)N * INCH * 2;   // 12.8 MB
    _Float16* P  = (_Float16*)(ws + off); off += (size_t)N * FDIM * 2;   // 25.6 MB
    float* ssrc = (float*)(ws + off); off += (size_t)N * HEADS * 4;
    float* sdst = (float*)(ws + off); off += (size_t)N * HEADS * 4;
    float* wcsr = (float*)(ws + off); off += (size_t)E * HEADS * 4;      // 8.8 MB
    float* aself = (float*)(ws + off); off += (size_t)N * HEADS * 4;
    int* rowstart = (int*)(ws + off); off += ((size_t)(N + 1) * 4 + 255) / 256 * 256;
    int* counts = (int*)(ws + off); off += (size_t)N * 4;
    int* cursor = (int*)(ws + off); off += (size_t)N * 4;
    int* csr_src = (int*)(ws + off); off += (size_t)E * 4;
    float* pooled = (float*)(ws + off); off += (size_t)NGRAPHS * FDIM * 4;
    int* bsum = (int*)(ws + off); off += ((size_t)((N + 255) / 256) * 4 + 255) / 256 * 256;
    _Float16* Wt[3];
    int Ks[3] = {INCH, FDIM, FDIM};
    for (int l = 0; l < 3; ++l) {
        Wt[l] = (_Float16*)(ws + off); off += (size_t)256 * Ks[l] * 2;
    }

    const int nb = (N + 255) / 256;

    // ---- CSR build ----
    hipMemsetAsync(counts, 0, (size_t)N * 4, stream);
    k_hist<<<(E + 255) / 256, 256, 0, stream>>>(e_dst, E, counts);
    k_blocksum<<<nb, 256, 0, stream>>>(counts, N, bsum);
    k_scanfinal<<<nb, 256, 0, stream>>>(counts, bsum, N, rowstart, cursor);
    k_scatter<<<(E + 255) / 256, 256, 0, stream>>>(e_src, e_dst, E, cursor, csr_src);

    // ---- input + weight conversion to f16 planes ----
    k_adecomp<<<((N * INCH / 4) + 255) / 256, 256, 0, stream>>>(x, xf, N * INCH / 4);
    for (int l = 0; l < 3; ++l)
        k_wdecomp<<<(Ks[l] * 256 + 255) / 256, 256, 0, stream>>>(W[l], Wt[l], Ks[l]);

    // ---- 3 GAT layers ----
    const _Float16* Af = xf;
    for (int l = 0; l < 3; ++l) {
        int K = Ks[l];
        k_gemm_mfma<<<(N + BM - 1) / BM, 256, 0, stream>>>(Af, Wt[l], asrc[l], adst[l],
                                                           hb, ssrc, sdst, N, K);
        k_edgew<<<(N * HEADS + 255) / 256, 256, 0, stream>>>(ssrc, sdst, rowstart, csr_src,
                                                             wcsr, aself, N);
        k_aggregate<<<(N + 3) / 4, 256, 0, stream>>>(hb, wcsr, aself, rowstart, csr_src,
                                                     bias[l], P, N);
        Af = P;
    }

    // ---- pool + classifier ----
    hipMemsetAsync(pooled, 0, (size_t)NGRAPHS * FDIM * 4, stream);
    k_pool<<<(N + 127) / 128, 256, 0, stream>>>(P, batch, pooled, N);
    k_final<<<4, 256, 0, stream>>>(pooled, Wc, bc, (float*)d_out);
}